// Round 9
// baseline (292.606 us; speedup 1.0000x reference)
//
#include <hip/hip_runtime.h>

typedef unsigned int u32;
typedef unsigned short u16;
typedef _Float16 f16;
typedef f16 f16x8 __attribute__((ext_vector_type(8)));
typedef float f32x4 __attribute__((ext_vector_type(4)));

#define NTH 256
#define SH1 72   // h1buf row stride in f16

__device__ __forceinline__ u32 pack2(float a, float b) {
    f16 fa = (f16)a, fb = (f16)b;
    return (u32)__builtin_bit_cast(u16, fa) | ((u32)__builtin_bit_cast(u16, fb) << 16);
}

// Single launch, 2048 blocks x 256 thr: block (i, seg) handles 512 candidates
// of row i (balanced ~2 conv groups/block vs r6's 4-10 — r4 counters showed
// tail-dominated occupancy). Conv2 = r6-verified MFMA. Per-segment max ->
// atomicMax f32-as-int into ws (0xAA poison = negative, always loses).
// Last-arriving block per row (done-counter, poison-deterministic) runs the
// f32 MLP head inline, reading pooled via identity-atomic RMWs (coherence
// point — safe under cross-XCD L2 non-coherence).
__global__ __launch_bounds__(NTH) void NetworkAction_86131274154571_kernel(
    const float* __restrict__ s,    const float* __restrict__ g,
    const float* __restrict__ w1g,  const float* __restrict__ b1g,
    const float* __restrict__ w2g,  const float* __restrict__ b2g,
    const float* __restrict__ fc1w, const float* __restrict__ fc1b,
    const float* __restrict__ fc2w, const float* __restrict__ fc2b,
    const float* __restrict__ fc3w, const float* __restrict__ fc3b,
    const float* __restrict__ fc4w, const float* __restrict__ fc4b,
    int* __restrict__ pooled,       // ws: 1024*128 f32-as-int
    int* __restrict__ done,         // ws: 1024 counters (poison 0xAAAAAAAA)
    float2* __restrict__ out)
{
    __shared__ float4 acts[512];
    __shared__ u16    idxs[512];
    __shared__ f16    h1buf[16][SH1];
    __shared__ float  w1s[320];
    __shared__ float  b1s[64];
    __shared__ int    cnt;
    __shared__ int    flag;
    __shared__ float  feat[132];
    __shared__ float  z1[64];
    __shared__ float  z2[128];
    __shared__ float  z3[64];
    __shared__ float  kk[4];

    const int tid  = threadIdx.x;
    const int lane = tid & 63;
    const int wave = tid >> 6;               // 0..3
    const int i    = blockIdx.x >> 1;        // row
    const int seg  = blockIdx.x & 1;         // candidate half

    if (tid == 0) cnt = 0;
    for (int q = tid; q < 320; q += NTH) w1s[q] = w1g[q];
    if (tid < 64) b1s[tid] = b1g[tid];

    const float4 si = ((const float4*)s)[i];

    // B-frags (r6-verified): wave owns channels 32w..32w+31 as two 16-N tiles
    const int n_base = wave * 32;
    const int ncol   = lane & 15;
    const int kq     = lane >> 4;
    f16x8 bfrag[2][2];
    float b2r[2];
    #pragma unroll
    for (int tile = 0; tile < 2; ++tile) {
        const int n = n_base + tile * 16 + ncol;
        b2r[tile] = b2g[n];
        #pragma unroll
        for (int t = 0; t < 2; ++t) {
            const float* wp = w2g + n * 64 + t * 32 + kq * 8;
            float4 lo = ((const float4*)wp)[0];
            float4 hi = ((const float4*)wp)[1];
            f16x8 b;
            b[0] = (f16)lo.x; b[1] = (f16)lo.y; b[2] = (f16)lo.z; b[3] = (f16)lo.w;
            b[4] = (f16)hi.x; b[5] = (f16)hi.y; b[6] = (f16)hi.z; b[7] = (f16)hi.w;
            bfrag[tile][t] = b;
        }
    }
    __syncthreads();   // cnt=0 + w1s/b1s visible

    // ---- scan this 512-candidate segment (coalesced), compact actives ----
    const int j0 = seg * 512;
    #pragma unroll
    for (int it = 0; it < 2; ++it) {
        const int j = j0 + it * NTH + tid;
        float4 sj = ((const float4*)s)[j];
        float dx = si.x - sj.x, dy = si.y - sj.y;
        if (dx * dx + dy * dy < 0.25f) {
            int slot = atomicAdd(&cnt, 1);
            acts[slot] = sj;
            idxs[slot] = (u16)j;
        }
    }
    __syncthreads();
    const int nact = cnt;                    // avg ~31 -> ~2 groups

    float mtile[2] = {0.0f, 0.0f};           // relu folded into max with 0

    for (int gb = 0; gb < nact; gb += 16) {
        #pragma unroll
        for (int it = 0; it < 2; ++it) {
            const int idx = it * NTH + tid;
            const int p = idx >> 5, c2 = idx & 31;
            if (gb + p < nact) {
                const float4 sj = acts[gb + p];
                const float x0 = si.x - sj.x, x1 = si.y - sj.y;
                const float x2 = si.z - sj.z, x3 = si.w - sj.w;
                const float x4 = (idxs[gb + p] == i) ? 1.0f : 0.0f;
                const int c = c2 * 2;
                const float* wa = &w1s[c * 5];
                float ha = b1s[c];
                ha = fmaf(wa[0], x0, ha); ha = fmaf(wa[1], x1, ha);
                ha = fmaf(wa[2], x2, ha); ha = fmaf(wa[3], x3, ha);
                ha = fmaf(wa[4], x4, ha);
                const float* wb = &w1s[c * 5 + 5];
                float hb = b1s[c + 1];
                hb = fmaf(wb[0], x0, hb); hb = fmaf(wb[1], x1, hb);
                hb = fmaf(wb[2], x2, hb); hb = fmaf(wb[3], x3, hb);
                hb = fmaf(wb[4], x4, hb);
                *(u32*)&h1buf[p][c2 * 2] = pack2(fmaxf(ha, 0.0f), fmaxf(hb, 0.0f));
            }
        }
        __syncthreads();

        f16x8 a0 = *(const f16x8*)&h1buf[ncol][kq * 8];
        f16x8 a1 = *(const f16x8*)&h1buf[ncol][32 + kq * 8];
        #pragma unroll
        for (int tile = 0; tile < 2; ++tile) {
            f32x4 acc = {0.0f, 0.0f, 0.0f, 0.0f};
            acc = __builtin_amdgcn_mfma_f32_16x16x32_f16(a0, bfrag[tile][0], acc, 0, 0, 0);
            acc = __builtin_amdgcn_mfma_f32_16x16x32_f16(a1, bfrag[tile][1], acc, 0, 0, 0);
            #pragma unroll
            for (int r = 0; r < 4; ++r) {
                const bool valid = (gb + kq * 4 + r) < nact;
                const float v = acc[r] + b2r[tile];
                mtile[tile] = valid ? fmaxf(mtile[tile], v) : mtile[tile];
            }
        }
        __syncthreads();
    }

    // reduce across kq quads; publish partial max (device-scope atomic)
    #pragma unroll
    for (int tile = 0; tile < 2; ++tile) {
        float m = mtile[tile];
        m = fmaxf(m, __shfl_xor(m, 16));
        m = fmaxf(m, __shfl_xor(m, 32));
        if (lane < 16)
            atomicMax(&pooled[i * 128 + n_base + tile * 16 + lane],
                      __float_as_int(m));
    }

    __threadfence();   // release pooled before bumping done
    if (tid == 0) {
        int old = atomicAdd(&done[i], 1);
        flag = (old == (int)0xAAAAAAABu) ? 1 : 0;   // 2nd arriver (poison+1)
    }
    __syncthreads();
    if (!flag) return;

    // ---- last arriver: f32 MLP head for row i (r4-validated logic) ----
    __threadfence();   // acquire
    if (tid < 128) {
        int pv = atomicAdd(&pooled[i * 128 + tid], 0);  // coherence-point read
        feat[tid] = __int_as_float(pv);
    }
    if (tid == 0) {
        float2 gv = ((const float2*)g)[i];
        feat[128] = si.x - gv.x;
        feat[129] = si.y - gv.y;
        feat[130] = si.z;
        feat[131] = si.w;
    }
    __syncthreads();

    if (tid < 64) {                          // fc1: 132 -> 64
        float acc = fc1b[tid];
        const float4* wv = (const float4*)(fc1w + tid * 132);
        #pragma unroll
        for (int q = 0; q < 33; ++q) {
            float4 u = wv[q];
            int k = q * 4;
            acc = fmaf(u.x, feat[k+0], acc);
            acc = fmaf(u.y, feat[k+1], acc);
            acc = fmaf(u.z, feat[k+2], acc);
            acc = fmaf(u.w, feat[k+3], acc);
        }
        z1[tid] = fmaxf(acc, 0.0f);
    }
    __syncthreads();

    if (tid < 128) {                         // fc2: 64 -> 128
        float acc = fc2b[tid];
        const float4* wv = (const float4*)(fc2w + tid * 64);
        #pragma unroll
        for (int q = 0; q < 16; ++q) {
            float4 u = wv[q];
            int k = q * 4;
            acc = fmaf(u.x, z1[k+0], acc);
            acc = fmaf(u.y, z1[k+1], acc);
            acc = fmaf(u.z, z1[k+2], acc);
            acc = fmaf(u.w, z1[k+3], acc);
        }
        z2[tid] = fmaxf(acc, 0.0f);
    }
    __syncthreads();

    if (tid < 64) {                          // fc3: 128 -> 64
        float acc = fc3b[tid];
        const float4* wv = (const float4*)(fc3w + tid * 128);
        #pragma unroll
        for (int q = 0; q < 32; ++q) {
            float4 u = wv[q];
            int k = q * 4;
            acc = fmaf(u.x, z2[k+0], acc);
            acc = fmaf(u.y, z2[k+1], acc);
            acc = fmaf(u.z, z2[k+2], acc);
            acc = fmaf(u.w, z2[k+3], acc);
        }
        z3[tid] = fmaxf(acc, 0.0f);
    }
    __syncthreads();

    if (tid < 4) {                           // fc4: 64 -> 4 + sigmoid gain
        float acc = fc4b[tid];
        const float4* wv = (const float4*)(fc4w + tid * 64);
        #pragma unroll
        for (int q = 0; q < 16; ++q) {
            float4 u = wv[q];
            int k = q * 4;
            acc = fmaf(u.x, z3[k+0], acc);
            acc = fmaf(u.y, z3[k+1], acc);
            acc = fmaf(u.z, z3[k+2], acc);
            acc = fmaf(u.w, z3[k+3], acc);
        }
        kk[tid] = 2.0f / (1.0f + expf(-acc)) - 1.0f;
    }
    __syncthreads();

    if (tid == 0) {
        float ax = -(kk[0] * feat[128] + kk[1] * feat[130]);
        float ay = -(kk[2] * feat[129] + kk[3] * feat[131]);
        out[i] = make_float2(ax, ay);
    }
}

extern "C" void kernel_launch(void* const* d_in, const int* in_sizes, int n_in,
                              void* d_out, int out_size, void* d_ws, size_t ws_size,
                              hipStream_t stream) {
    const float* s    = (const float*)d_in[0];
    const float* g    = (const float*)d_in[1];
    const float* c1w  = (const float*)d_in[2];
    const float* c1b  = (const float*)d_in[3];
    const float* c2w  = (const float*)d_in[4];
    const float* c2b  = (const float*)d_in[5];
    const float* fc1w = (const float*)d_in[6];
    const float* fc1b = (const float*)d_in[7];
    const float* fc2w = (const float*)d_in[8];
    const float* fc2b = (const float*)d_in[9];
    const float* fc3w = (const float*)d_in[10];
    const float* fc3b = (const float*)d_in[11];
    const float* fc4w = (const float*)d_in[12];
    const float* fc4b = (const float*)d_in[13];

    int* pooled = (int*)d_ws;                     // 512 KB
    int* done   = (int*)d_ws + 1024 * 128;        // 4 KB
    float2* out = (float2*)d_out;

    NetworkAction_86131274154571_kernel<<<2048, NTH, 0, stream>>>(
        s, g, c1w, c1b, c2w, c2b, fc1w, fc1b, fc2w, fc2b,
        fc3w, fc3b, fc4w, fc4b, pooled, done, out);
}

// Round 10
// 104.861 us; speedup vs baseline: 2.7904x; 2.7904x over previous
//
#include <hip/hip_runtime.h>

typedef unsigned int u32;
typedef unsigned short u16;
typedef _Float16 f16;
typedef f16 f16x8 __attribute__((ext_vector_type(8)));
typedef float f32x4 __attribute__((ext_vector_type(4)));

#define NTH 256
#define SH1 72   // h1buf row stride in f16

__device__ __forceinline__ u32 pack2(float a, float b) {
    f16 fa = (f16)a, fb = (f16)b;
    return (u32)__builtin_bit_cast(u16, fa) | ((u32)__builtin_bit_cast(u16, fb) << 16);
}

// K1: block (i, seg) handles 512 candidates of row i (balanced ~2 conv
// groups/block). Conv2 = r6-verified MFMA. Per-segment max -> atomicMax
// f32-as-int into ws (r5-proven: 0xAA poison is a negative int, always
// loses; all published values >= 0 since relu is folded into the max).
// NO fences / last-arriver — r9 post-mortem: device-scope fence + cross-XCD
// done-counter machinery parked the chip (56% occupancy, 2.6% VALUBusy).
// The kernel boundary is the coherence point.
__global__ __launch_bounds__(NTH) void pool_seg_kernel(
    const float* __restrict__ s,
    const float* __restrict__ w1g, const float* __restrict__ b1g,
    const float* __restrict__ w2g, const float* __restrict__ b2g,
    int* __restrict__ pooled)
{
    __shared__ float4 acts[512];
    __shared__ u16    idxs[512];
    __shared__ f16    h1buf[16][SH1];
    __shared__ float  w1s[320];
    __shared__ float  b1s[64];
    __shared__ int    cnt;

    const int tid  = threadIdx.x;
    const int lane = tid & 63;
    const int wave = tid >> 6;               // 0..3
    const int i    = blockIdx.x >> 1;        // row
    const int seg  = blockIdx.x & 1;         // candidate half

    if (tid == 0) cnt = 0;
    for (int q = tid; q < 320; q += NTH) w1s[q] = w1g[q];
    if (tid < 64) b1s[tid] = b1g[tid];

    const float4 si = ((const float4*)s)[i];

    // B-frags (r6-verified): wave owns channels 32w..32w+31 as two 16-N tiles
    const int n_base = wave * 32;
    const int ncol   = lane & 15;
    const int kq     = lane >> 4;
    f16x8 bfrag[2][2];
    float b2r[2];
    #pragma unroll
    for (int tile = 0; tile < 2; ++tile) {
        const int n = n_base + tile * 16 + ncol;
        b2r[tile] = b2g[n];
        #pragma unroll
        for (int t = 0; t < 2; ++t) {
            const float* wp = w2g + n * 64 + t * 32 + kq * 8;
            float4 lo = ((const float4*)wp)[0];
            float4 hi = ((const float4*)wp)[1];
            f16x8 b;
            b[0] = (f16)lo.x; b[1] = (f16)lo.y; b[2] = (f16)lo.z; b[3] = (f16)lo.w;
            b[4] = (f16)hi.x; b[5] = (f16)hi.y; b[6] = (f16)hi.z; b[7] = (f16)hi.w;
            bfrag[tile][t] = b;
        }
    }
    __syncthreads();   // cnt=0 + w1s/b1s visible

    // scan this 512-candidate segment (coalesced), compact actives
    const int j0 = seg * 512;
    #pragma unroll
    for (int it = 0; it < 2; ++it) {
        const int j = j0 + it * NTH + tid;
        float4 sj = ((const float4*)s)[j];
        float dx = si.x - sj.x, dy = si.y - sj.y;
        if (dx * dx + dy * dy < 0.25f) {
            int slot = atomicAdd(&cnt, 1);
            acts[slot] = sj;
            idxs[slot] = (u16)j;
        }
    }
    __syncthreads();
    const int nact = cnt;                    // avg ~31 -> ~2 groups

    float mtile[2] = {0.0f, 0.0f};           // relu folded into max with 0

    for (int gb = 0; gb < nact; gb += 16) {
        #pragma unroll
        for (int it = 0; it < 2; ++it) {
            const int idx = it * NTH + tid;
            const int p = idx >> 5, c2 = idx & 31;
            if (gb + p < nact) {
                const float4 sj = acts[gb + p];
                const float x0 = si.x - sj.x, x1 = si.y - sj.y;
                const float x2 = si.z - sj.z, x3 = si.w - sj.w;
                const float x4 = (idxs[gb + p] == i) ? 1.0f : 0.0f;
                const int c = c2 * 2;
                const float* wa = &w1s[c * 5];
                float ha = b1s[c];
                ha = fmaf(wa[0], x0, ha); ha = fmaf(wa[1], x1, ha);
                ha = fmaf(wa[2], x2, ha); ha = fmaf(wa[3], x3, ha);
                ha = fmaf(wa[4], x4, ha);
                const float* wb = &w1s[c * 5 + 5];
                float hb = b1s[c + 1];
                hb = fmaf(wb[0], x0, hb); hb = fmaf(wb[1], x1, hb);
                hb = fmaf(wb[2], x2, hb); hb = fmaf(wb[3], x3, hb);
                hb = fmaf(wb[4], x4, hb);
                *(u32*)&h1buf[p][c2 * 2] = pack2(fmaxf(ha, 0.0f), fmaxf(hb, 0.0f));
            }
        }
        __syncthreads();

        f16x8 a0 = *(const f16x8*)&h1buf[ncol][kq * 8];
        f16x8 a1 = *(const f16x8*)&h1buf[ncol][32 + kq * 8];
        #pragma unroll
        for (int tile = 0; tile < 2; ++tile) {
            f32x4 acc = {0.0f, 0.0f, 0.0f, 0.0f};
            acc = __builtin_amdgcn_mfma_f32_16x16x32_f16(a0, bfrag[tile][0], acc, 0, 0, 0);
            acc = __builtin_amdgcn_mfma_f32_16x16x32_f16(a1, bfrag[tile][1], acc, 0, 0, 0);
            #pragma unroll
            for (int r = 0; r < 4; ++r) {
                const bool valid = (gb + kq * 4 + r) < nact;
                const float v = acc[r] + b2r[tile];
                mtile[tile] = valid ? fmaxf(mtile[tile], v) : mtile[tile];
            }
        }
        __syncthreads();
    }

    // reduce across kq quads; publish partial max (device-scope atomic)
    #pragma unroll
    for (int tile = 0; tile < 2; ++tile) {
        float m = mtile[tile];
        m = fmaxf(m, __shfl_xor(m, 16));
        m = fmaxf(m, __shfl_xor(m, 32));
        if (lane < 16)
            atomicMax(&pooled[i * 128 + n_base + tile * 16 + lane],
                      __float_as_int(m));
    }
}

#define RB 4

// K2: f32 MLP head, 4 rows per block (256 blocks x 256 thr). Plain loads of
// pooled across the dispatch boundary (r5-proven coherent). r4-validated math.
__global__ __launch_bounds__(NTH) void head4_kernel(
    const float* __restrict__ s,    const float* __restrict__ g,
    const float* __restrict__ fc1w, const float* __restrict__ fc1b,
    const float* __restrict__ fc2w, const float* __restrict__ fc2b,
    const float* __restrict__ fc3w, const float* __restrict__ fc3b,
    const float* __restrict__ fc4w, const float* __restrict__ fc4b,
    const int* __restrict__ pooled,
    float2* __restrict__ out)
{
    __shared__ float feat[RB][132];
    __shared__ float z1[RB][64];
    __shared__ float z2[RB][128];
    __shared__ float z3[RB][64];
    __shared__ float kk[RB][4];

    const int tid = threadIdx.x;
    const int r0  = blockIdx.x * RB;

    for (int idx = tid; idx < RB * 128; idx += NTH) {
        const int row = idx >> 7, c = idx & 127;
        feat[row][c] = __int_as_float(pooled[(r0 + row) * 128 + c]);
    }
    if (tid < RB) {
        const int i = r0 + tid;
        float4 sv = ((const float4*)s)[i];
        float2 gv = ((const float2*)g)[i];
        feat[tid][128] = sv.x - gv.x;
        feat[tid][129] = sv.y - gv.y;
        feat[tid][130] = sv.z;
        feat[tid][131] = sv.w;
    }
    __syncthreads();

    {   // fc1: 132 -> 64, all 256 threads (4 rows x 64 ch)
        const int row = tid >> 6, c = tid & 63;
        float acc = fc1b[c];
        const float4* wv = (const float4*)(fc1w + c * 132);
        #pragma unroll
        for (int q = 0; q < 33; ++q) {
            float4 u = wv[q];
            int k = q * 4;
            acc = fmaf(u.x, feat[row][k+0], acc);
            acc = fmaf(u.y, feat[row][k+1], acc);
            acc = fmaf(u.z, feat[row][k+2], acc);
            acc = fmaf(u.w, feat[row][k+3], acc);
        }
        z1[row][c] = fmaxf(acc, 0.0f);
    }
    __syncthreads();

    for (int idx = tid; idx < RB * 128; idx += NTH) {   // fc2: 64 -> 128
        const int row = idx >> 7, c = idx & 127;
        float acc = fc2b[c];
        const float4* wv = (const float4*)(fc2w + c * 64);
        #pragma unroll
        for (int q = 0; q < 16; ++q) {
            float4 u = wv[q];
            int k = q * 4;
            acc = fmaf(u.x, z1[row][k+0], acc);
            acc = fmaf(u.y, z1[row][k+1], acc);
            acc = fmaf(u.z, z1[row][k+2], acc);
            acc = fmaf(u.w, z1[row][k+3], acc);
        }
        z2[row][c] = fmaxf(acc, 0.0f);
    }
    __syncthreads();

    {   // fc3: 128 -> 64, all 256 threads
        const int row = tid >> 6, c = tid & 63;
        float acc = fc3b[c];
        const float4* wv = (const float4*)(fc3w + c * 128);
        #pragma unroll
        for (int q = 0; q < 32; ++q) {
            float4 u = wv[q];
            int k = q * 4;
            acc = fmaf(u.x, z2[row][k+0], acc);
            acc = fmaf(u.y, z2[row][k+1], acc);
            acc = fmaf(u.z, z2[row][k+2], acc);
            acc = fmaf(u.w, z2[row][k+3], acc);
        }
        z3[row][c] = fmaxf(acc, 0.0f);
    }
    __syncthreads();

    if (tid < RB * 4) {   // fc4: 64 -> 4 + sigmoid gain
        const int row = tid >> 2, mi = tid & 3;
        float acc = fc4b[mi];
        const float4* wv = (const float4*)(fc4w + mi * 64);
        #pragma unroll
        for (int q = 0; q < 16; ++q) {
            float4 u = wv[q];
            int k = q * 4;
            acc = fmaf(u.x, z3[row][k+0], acc);
            acc = fmaf(u.y, z3[row][k+1], acc);
            acc = fmaf(u.z, z3[row][k+2], acc);
            acc = fmaf(u.w, z3[row][k+3], acc);
        }
        kk[row][mi] = 2.0f / (1.0f + expf(-acc)) - 1.0f;
    }
    __syncthreads();

    if (tid < RB) {
        float ax = -(kk[tid][0] * feat[tid][128] + kk[tid][1] * feat[tid][130]);
        float ay = -(kk[tid][2] * feat[tid][129] + kk[tid][3] * feat[tid][131]);
        out[r0 + tid] = make_float2(ax, ay);
    }
}

extern "C" void kernel_launch(void* const* d_in, const int* in_sizes, int n_in,
                              void* d_out, int out_size, void* d_ws, size_t ws_size,
                              hipStream_t stream) {
    const float* s    = (const float*)d_in[0];
    const float* g    = (const float*)d_in[1];
    const float* c1w  = (const float*)d_in[2];
    const float* c1b  = (const float*)d_in[3];
    const float* c2w  = (const float*)d_in[4];
    const float* c2b  = (const float*)d_in[5];
    const float* fc1w = (const float*)d_in[6];
    const float* fc1b = (const float*)d_in[7];
    const float* fc2w = (const float*)d_in[8];
    const float* fc2b = (const float*)d_in[9];
    const float* fc3w = (const float*)d_in[10];
    const float* fc3b = (const float*)d_in[11];
    const float* fc4w = (const float*)d_in[12];
    const float* fc4b = (const float*)d_in[13];

    int* pooled = (int*)d_ws;        // 1024*128 f32-as-int = 512 KB
    float2* out = (float2*)d_out;

    pool_seg_kernel<<<2048, NTH, 0, stream>>>(s, c1w, c1b, c2w, c2b, pooled);
    head4_kernel<<<256, NTH, 0, stream>>>(s, g, fc1w, fc1b, fc2w, fc2b,
                                          fc3w, fc3b, fc4w, fc4b, pooled, out);
}

// Round 11
// 100.603 us; speedup vs baseline: 2.9085x; 1.0423x over previous
//
#include <hip/hip_runtime.h>

typedef unsigned int u32;
typedef unsigned short u16;
typedef _Float16 f16;
typedef f16 f16x8 __attribute__((ext_vector_type(8)));
typedef float f32x4 __attribute__((ext_vector_type(4)));

#define NTH 256
#define SH1 72   // h1buf row stride in f16 (144 B = 9*16: rows 16B-aligned, 2-way banks = free)

__device__ __forceinline__ u32 pack2(float a, float b) {
    f16 fa = (f16)a, fb = (f16)b;
    return (u32)__builtin_bit_cast(u16, fa) | ((u32)__builtin_bit_cast(u16, fb) << 16);
}

// r6 fused structure (best measured: kernel ~27us) with the serial chain cut:
//  - no slds staging: s (16 KB) lives in L1; scan warms it, conv1 broadcast-hits
//  - 32-pair groups, double-buffered h1 -> 1 barrier/group (r8-verified parity)
//  - head fused in-block (r7/r10 counter-backed: splitting it always lost)
// One 256-thread block (4 waves) per row i.
__global__ __launch_bounds__(NTH) void NetworkAction_86131274154571_kernel(
    const float* __restrict__ s,    const float* __restrict__ g,
    const float* __restrict__ w1g,  const float* __restrict__ b1g,
    const float* __restrict__ w2g,  const float* __restrict__ b2g,
    const float* __restrict__ fc1w, const float* __restrict__ fc1b,
    const float* __restrict__ fc2w, const float* __restrict__ fc2b,
    const float* __restrict__ fc3w, const float* __restrict__ fc3b,
    const float* __restrict__ fc4w, const float* __restrict__ fc4b,
    float2* __restrict__ out)
{
    __shared__ u16   idx[1024];        // active-j list
    __shared__ f16   h1buf[2][32][SH1];// double-buffered conv1 outputs
    __shared__ float w1s[320];
    __shared__ float b1s[64];
    __shared__ int   cnt;
    __shared__ float feat[132];
    __shared__ float z1[64];
    __shared__ float z2[128];
    __shared__ float z3[64];
    __shared__ float kk[4];

    const int tid  = threadIdx.x;
    const int lane = tid & 63;
    const int wave = tid >> 6;          // 0..3
    const int i    = blockIdx.x;

    if (tid == 0) cnt = 0;
    for (int q = tid; q < 320; q += NTH) w1s[q] = w1g[q];
    if (tid < 64) b1s[tid] = b1g[tid];

    const float4 si = ((const float4*)s)[i];

    // B-frags (r6-verified): wave owns channels 32w..32w+31 as two 16-N tiles
    const int n_base = wave * 32;
    const int ncol   = lane & 15;
    const int kq     = lane >> 4;
    f16x8 bfrag[2][2];
    float b2r[2];
    #pragma unroll
    for (int tile = 0; tile < 2; ++tile) {
        const int n = n_base + tile * 16 + ncol;
        b2r[tile] = b2g[n];
        #pragma unroll
        for (int t = 0; t < 2; ++t) {
            const float* wp = w2g + n * 64 + t * 32 + kq * 8;
            float4 lo = ((const float4*)wp)[0];
            float4 hi = ((const float4*)wp)[1];
            f16x8 b;
            b[0] = (f16)lo.x; b[1] = (f16)lo.y; b[2] = (f16)lo.z; b[3] = (f16)lo.w;
            b[4] = (f16)hi.x; b[5] = (f16)hi.y; b[6] = (f16)hi.z; b[7] = (f16)hi.w;
            bfrag[tile][t] = b;
        }
    }
    __syncthreads();   // cnt=0 + w1s/b1s staged

    // ---- scan all 1024 candidates (coalesced; warms L1), compact indices ----
    #pragma unroll
    for (int p = 0; p < 4; ++p) {
        const int j = p * NTH + tid;
        float4 sj = ((const float4*)s)[j];
        float dx = si.x - sj.x, dy = si.y - sj.y;
        if (dx * dx + dy * dy < 0.25f)
            idx[atomicAdd(&cnt, 1)] = (u16)j;
    }
    __syncthreads();
    const int nact = cnt;               // >=1 (diagonal)

    float mtile[2] = {0.0f, 0.0f};      // relu folded into max with 0

    // ---- conv groups of 32 pairs, dbuf, ONE barrier per group ----
    int buf = 0;
    for (int gb = 0; gb < nact; gb += 32) {
        // conv1: 32 pairs x 32 ch-pairs = 1024 items over 256 threads
        #pragma unroll
        for (int it = 0; it < 4; ++it) {
            const int item = it * NTH + tid;
            const int p = item >> 5, c2 = item & 31;
            if (gb + p < nact) {
                const int j = idx[gb + p];
                const float4 sj = ((const float4*)s)[j];  // L1 broadcast hit
                const float x0 = si.x - sj.x, x1 = si.y - sj.y;
                const float x2 = si.z - sj.z, x3 = si.w - sj.w;
                const float x4 = (j == i) ? 1.0f : 0.0f;
                const int c = c2 * 2;
                const float* wa = &w1s[c * 5];
                float ha = b1s[c];
                ha = fmaf(wa[0], x0, ha); ha = fmaf(wa[1], x1, ha);
                ha = fmaf(wa[2], x2, ha); ha = fmaf(wa[3], x3, ha);
                ha = fmaf(wa[4], x4, ha);
                const float* wb = wa + 5;
                float hb = b1s[c + 1];
                hb = fmaf(wb[0], x0, hb); hb = fmaf(wb[1], x1, hb);
                hb = fmaf(wb[2], x2, hb); hb = fmaf(wb[3], x3, hb);
                hb = fmaf(wb[4], x4, hb);
                *(u32*)&h1buf[buf][p][c2 * 2] = pack2(fmaxf(ha, 0.0f), fmaxf(hb, 0.0f));
            }
        }
        __syncthreads();   // the only barrier this group (dbuf parity fences reuse)

        #pragma unroll
        for (int ph = 0; ph < 2; ++ph) {           // two 16-pair A-tiles
            f16x8 a0 = *(const f16x8*)&h1buf[buf][ph * 16 + ncol][kq * 8];
            f16x8 a1 = *(const f16x8*)&h1buf[buf][ph * 16 + ncol][32 + kq * 8];
            #pragma unroll
            for (int tile = 0; tile < 2; ++tile) {
                f32x4 acc = {0.0f, 0.0f, 0.0f, 0.0f};
                acc = __builtin_amdgcn_mfma_f32_16x16x32_f16(a0, bfrag[tile][0], acc, 0, 0, 0);
                acc = __builtin_amdgcn_mfma_f32_16x16x32_f16(a1, bfrag[tile][1], acc, 0, 0, 0);
                #pragma unroll
                for (int r = 0; r < 4; ++r) {
                    const bool valid = (gb + ph * 16 + kq * 4 + r) < nact;
                    const float v = acc[r] + b2r[tile];
                    mtile[tile] = valid ? fmaxf(mtile[tile], v) : mtile[tile];
                }
            }
        }
        buf ^= 1;
    }

    // reduce across kq quads (same channel col lr)
    #pragma unroll
    for (int tile = 0; tile < 2; ++tile) {
        float m = mtile[tile];
        m = fmaxf(m, __shfl_xor(m, 16));
        m = fmaxf(m, __shfl_xor(m, 32));
        if (lane < 16) feat[n_base + tile * 16 + lane] = m;
    }
    if (tid == 0) {
        float2 gv = ((const float2*)g)[i];
        feat[128] = si.x - gv.x;
        feat[129] = si.y - gv.y;
        feat[130] = si.z;
        feat[131] = si.w;
    }
    __syncthreads();

    // ---- MLP head (r4/r6-validated f32 logic) ----
    if (tid < 64) {                     // fc1: 132 -> 64
        float acc = fc1b[tid];
        const float4* wv = (const float4*)(fc1w + tid * 132);
        #pragma unroll
        for (int q = 0; q < 33; ++q) {
            float4 u = wv[q];
            int k = q * 4;
            acc = fmaf(u.x, feat[k+0], acc);
            acc = fmaf(u.y, feat[k+1], acc);
            acc = fmaf(u.z, feat[k+2], acc);
            acc = fmaf(u.w, feat[k+3], acc);
        }
        z1[tid] = fmaxf(acc, 0.0f);
    }
    __syncthreads();

    if (tid < 128) {                    // fc2: 64 -> 128
        float acc = fc2b[tid];
        const float4* wv = (const float4*)(fc2w + tid * 64);
        #pragma unroll
        for (int q = 0; q < 16; ++q) {
            float4 u = wv[q];
            int k = q * 4;
            acc = fmaf(u.x, z1[k+0], acc);
            acc = fmaf(u.y, z1[k+1], acc);
            acc = fmaf(u.z, z1[k+2], acc);
            acc = fmaf(u.w, z1[k+3], acc);
        }
        z2[tid] = fmaxf(acc, 0.0f);
    }
    __syncthreads();

    if (tid < 64) {                     // fc3: 128 -> 64
        float acc = fc3b[tid];
        const float4* wv = (const float4*)(fc3w + tid * 128);
        #pragma unroll
        for (int q = 0; q < 32; ++q) {
            float4 u = wv[q];
            int k = q * 4;
            acc = fmaf(u.x, z2[k+0], acc);
            acc = fmaf(u.y, z2[k+1], acc);
            acc = fmaf(u.z, z2[k+2], acc);
            acc = fmaf(u.w, z2[k+3], acc);
        }
        z3[tid] = fmaxf(acc, 0.0f);
    }
    __syncthreads();

    if (tid < 4) {                      // fc4: 64 -> 4 + sigmoid gain
        float acc = fc4b[tid];
        const float4* wv = (const float4*)(fc4w + tid * 64);
        #pragma unroll
        for (int q = 0; q < 16; ++q) {
            float4 u = wv[q];
            int k = q * 4;
            acc = fmaf(u.x, z3[k+0], acc);
            acc = fmaf(u.y, z3[k+1], acc);
            acc = fmaf(u.z, z3[k+2], acc);
            acc = fmaf(u.w, z3[k+3], acc);
        }
        kk[tid] = 2.0f / (1.0f + expf(-acc)) - 1.0f;
    }
    __syncthreads();

    if (tid == 0) {
        float ax = -(kk[0] * feat[128] + kk[1] * feat[130]);
        float ay = -(kk[2] * feat[129] + kk[3] * feat[131]);
        out[i] = make_float2(ax, ay);
    }
}

extern "C" void kernel_launch(void* const* d_in, const int* in_sizes, int n_in,
                              void* d_out, int out_size, void* d_ws, size_t ws_size,
                              hipStream_t stream) {
    const float* s    = (const float*)d_in[0];
    const float* g    = (const float*)d_in[1];
    const float* c1w  = (const float*)d_in[2];
    const float* c1b  = (const float*)d_in[3];
    const float* c2w  = (const float*)d_in[4];
    const float* c2b  = (const float*)d_in[5];
    const float* fc1w = (const float*)d_in[6];
    const float* fc1b = (const float*)d_in[7];
    const float* fc2w = (const float*)d_in[8];
    const float* fc2b = (const float*)d_in[9];
    const float* fc3w = (const float*)d_in[10];
    const float* fc3b = (const float*)d_in[11];
    const float* fc4w = (const float*)d_in[12];
    const float* fc4b = (const float*)d_in[13];

    float2* out = (float2*)d_out;

    NetworkAction_86131274154571_kernel<<<1024, NTH, 0, stream>>>(
        s, g, c1w, c1b, c2w, c2b, fc1w, fc1b, fc2w, fc2b,
        fc3w, fc3b, fc4w, fc4b, out);
}